// Round 5
// baseline (702.825 us; speedup 1.0000x reference)
//
#include <hip/hip_runtime.h>

// Problem dims
#define B_  4096
#define T_  128
#define NL  256
#define NS  64
#define NO  32
#define V_  64
#define RB  16            // rows per block
#define NBLK (B_ / RB)    // 256 blocks

typedef __bf16 bf16;
typedef bf16  bf16x8 __attribute__((ext_vector_type(8)));
typedef bf16  bf16x4 __attribute__((ext_vector_type(4)));
typedef float f32x4  __attribute__((ext_vector_type(4)));

#define MF(a, b, c) __builtin_amdgcn_mfma_f32_16x16x32_bf16(a, b, c, 0, 0, 0)

// Barrier WITHOUT vmcnt drain: all cross-barrier data is in VGPRs (weight
// prefetch ring); only LDS (x, Sp) needs ordering -> lgkmcnt(0)+s_barrier.
// __syncthreads() would emit s_waitcnt vmcnt(0) and stall the prefetch ring.
__device__ __forceinline__ void block_sync_lds() {
    asm volatile("s_waitcnt lgkmcnt(0)\ns_barrier" ::: "memory");
}

// ---------------------------------------------------------------------------
// Split fp32 weights -> bf16 hi/lo planes in MFMA A-fragment order:
//   dest[(((s*NT + t)*8 + ks)*512) + L*8 + j] = W[s][t*16 + (L&15)][ks*32 + (L>>4)*8 + j]
// so a wave's fragment load is one contiguous 1 KB global_load_dwordx4.
// ---------------------------------------------------------------------------
template <int TSHIFT>
__global__ void split_w_frag(const float* __restrict__ src,
                             bf16* __restrict__ hi, bf16* __restrict__ lo,
                             int total4) {
    int t4 = blockIdx.x * blockDim.x + threadIdx.x;
    if (t4 >= total4) return;
    const int jb   = (t4 & 1) * 4;
    const int L    = (t4 >> 1) & 63;
    const int ks   = (t4 >> 7) & 7;
    const int rest = t4 >> 10;
    const int t    = rest & ((1 << TSHIFT) - 1);
    const int s    = rest >> TSHIFT;
    const int row  = ((s << TSHIFT) + t) * 16 + (L & 15);
    const int k    = ks * 32 + (L >> 4) * 8 + jb;
    const float4 v = *(const float4*)(src + (size_t)row * NL + k);
    float vv[4] = {v.x, v.y, v.z, v.w};
    bf16x4 h, l;
#pragma unroll
    for (int e = 0; e < 4; e++) {
        bf16 hh = (bf16)vv[e];
        h[e] = hh;
        l[e] = (bf16)(vv[e] - (float)hh);
    }
    *(bf16x4*)(hi + (size_t)t4 * 4) = h;
    *(bf16x4*)(lo + (size_t)t4 * 4) = l;
}

// inv[s][v] = last j with out_idx[s][j]==v, else -1 (numpy last-dup-wins)
__global__ void inv_kernel(const int* __restrict__ out_idx, int* __restrict__ inv) {
    int t = blockIdx.x * blockDim.x + threadIdx.x;
    if (t >= NS * V_) return;
    int s = t >> 6, v = t & 63;
    int jf = -1;
#pragma unroll
    for (int j = 0; j < NO; j++)
        if (out_idx[(s << 5) | j] == v) jf = j;
    inv[t] = jf;
}

__device__ __forceinline__ float fast_tanh(float z) {
    float e = __expf(2.0f * z);
    return 1.0f - 2.0f / (e + 1.0f);
}

// x fragment-order address for element (batch row n, k = t*16 + q*4):
__device__ __forceinline__ int xaddr(int t, int q, int n) {
    return ((t >> 1) * 512) + (((t & 1) * 2 + (q >> 1)) * 128) + n * 8 + (q & 1) * 4;
}

// ---------------------------------------------------------------------------
// Persistent per-block recurrence. RB=16 rows/block, 256 blocks, 16 waves.
// Wave w: GEMM1 col-tile w (16 cols, 24 MFMA); GEMM2 task (t=w&1, ks=w>>1).
// One (vmcnt-free) barrier per step. 8-slot rolling weight ring: slot ks is
// refilled with NEXT step's ks fragment right after consumption, so every
// weight load has ~a full step of latency slack and VMEM issue is even.
// ---------------------------------------------------------------------------
__launch_bounds__(1024, 4)
__global__ void lalr_main(const float* __restrict__ latent0,
                          const float* __restrict__ b1,
                          const float* __restrict__ b2,
                          const int*   __restrict__ state_seq,
                          const int*   __restrict__ inv,
                          const bf16*  __restrict__ W1h, const bf16* __restrict__ W1l,
                          const bf16*  __restrict__ W2h, const bf16* __restrict__ W2l,
                          float* __restrict__ out) {
    __shared__ bf16  xh[2][4096];        // 16 KB  (frag order, double buffered)
    __shared__ bf16  xl[2][4096];        // 16 KB
    __shared__ float Sp[2][8][16][36];   // 36 KB  GEMM2 K-partials (pad 36)

    const int tid  = threadIdx.x;
    const int wave = tid >> 6;           // 0..15
    const int lane = tid & 63;
    const int n    = lane & 15;          // batch row
    const int q    = lane >> 4;          // quad
    const int r0   = blockIdx.x * RB;
    const int t2   = wave & 1;           // GEMM2 col-tile
    const int ks2  = wave >> 1;          // GEMM2 K-slice

    // ---- init: latent0 -> x[0] fragments (1 float4 per thread) ----
    {
        float4 v = *(const float4*)(latent0 + (size_t)(r0 + n) * NL + wave * 16 + q * 4);
        float vv[4] = {v.x, v.y, v.z, v.w};
        bf16x4 hv, lv;
#pragma unroll
        for (int e = 0; e < 4; e++) {
            bf16 hh = (bf16)vv[e];
            hv[e] = hh;
            lv[e] = (bf16)(vv[e] - (float)hh);
        }
        const int a = xaddr(wave, q, n);
        *(bf16x4*)(&xh[0][a]) = hv;
        *(bf16x4*)(&xl[0][a]) = lv;
    }

    int s0 = state_seq[0], s1 = -1, s2 = -1;

    // 8-slot ring: preload all of W1[s0] for this wave's col-tile (16 KB)
    bf16x8 pwh[8], pwl[8];
    {
        const bf16* w1hb = W1h + ((size_t)(s0 * 16 + wave) * 8) * 512;
        const bf16* w1lb = W1l + ((size_t)(s0 * 16 + wave) * 8) * 512;
#pragma unroll
        for (int p = 0; p < 8; p++) {
            pwh[p] = *(const bf16x8*)(w1hb + p * 512 + lane * 8);
            pwl[p] = *(const bf16x8*)(w1lb + p * 512 + lane * 8);
        }
    }
    bf16x8 w2h2, w2l2;   // GEMM2 frags for next iteration

    block_sync_lds();

    for (int i = 0; i <= T_ + 1; i++) {
        const int ib  = i & 1;
        const int cur = ib;               // x buffer read this iteration

        const int ns0 = (i + 1 < T_) ? state_seq[i + 1] : -1;
        const int pfs = (ns0 >= 0) ? ns0 : 0;   // safe prefetch state
        const bf16* nw1hb = W1h + ((size_t)(pfs * 16 + wave) * 8) * 512;
        const bf16* nw1lb = W1l + ((size_t)(pfs * 16 + wave) * 8) * 512;

        // b1 slice for this step (full-loop prefetch distance to tanh use)
        float4 bb1;
        if (s0 >= 0) bb1 = *(const float4*)(b1 + s0 * NL + wave * 16 + q * 4);

        // ---- GEMM1 (state s0): col-tile `wave`, full K=256, rolling ring ----
        f32x4 acc1;
        if (s0 >= 0) {
            acc1 = (f32x4){0.f, 0.f, 0.f, 0.f};
#pragma unroll
            for (int ks = 0; ks < 8; ks++) {
                bf16x8 xa = *(const bf16x8*)(&xh[cur][ks * 512 + lane * 8]);
                bf16x8 xb = *(const bf16x8*)(&xl[cur][ks * 512 + lane * 8]);
                bf16x8 wh = pwh[ks], wl = pwl[ks];
                // refill slot with NEXT step's fragment (≈1 full step of slack)
                pwh[ks] = *(const bf16x8*)(nw1hb + ks * 512 + lane * 8);
                pwl[ks] = *(const bf16x8*)(nw1lb + ks * 512 + lane * 8);
                acc1 = MF(wh, xa, acc1);
                acc1 = MF(wl, xa, acc1);
                acc1 = MF(wh, xb, acc1);
            }
        }

        // ---- GEMM2 (state s1): task (t2, ks2) ----
        if (s1 >= 0) {
            bf16x8 xa = *(const bf16x8*)(&xh[cur][ks2 * 512 + lane * 8]);
            bf16x8 xb = *(const bf16x8*)(&xl[cur][ks2 * 512 + lane * 8]);
            f32x4 a2 = (f32x4){0.f, 0.f, 0.f, 0.f};
            a2 = MF(w2h2, xa, a2);
            a2 = MF(w2l2, xa, a2);
            a2 = MF(w2h2, xb, a2);
            if (ks2 == 0) {
                float4 bb = *(const float4*)(b2 + s1 * NO + t2 * 16 + q * 4);
                a2[0] += bb.x; a2[1] += bb.y; a2[2] += bb.z; a2[3] += bb.w;
            }
            *(f32x4*)(&Sp[ib][ks2][n][t2 * 16 + q * 4]) = a2;
        }

        // ---- W2 prefetch for next iteration (state of next iter's s1 = s0) ----
        if (s0 >= 0) {
            const bf16* w2hb = W2h + ((size_t)((s0 * 2 + t2) * 8 + ks2)) * 512;
            const bf16* w2lb = W2l + ((size_t)((s0 * 2 + t2) * 8 + ks2)) * 512;
            w2h2 = *(const bf16x8*)(w2hb + lane * 8);
            w2l2 = *(const bf16x8*)(w2lb + lane * 8);
        }

        // ---- softmax + shfl-scatter + store for step i-2 (first 4 waves) ----
        if (s2 >= 0 && tid < 256) {
            const int r  = tid >> 4;
            const int j0 = tid & 15;
            const int pb = (i - 1) & 1;
            float v0 = 0.f, v1 = 0.f;
#pragma unroll
            for (int w = 0; w < 8; w++) {
                v0 += Sp[pb][w][r][j0];
                v1 += Sp[pb][w][r][j0 + 16];
            }
            float m = fmaxf(v0, v1);
#pragma unroll
            for (int d = 1; d < 16; d <<= 1) m = fmaxf(m, __shfl_xor(m, d));
            float e0 = __expf(v0 - m), e1 = __expf(v1 - m);
            float su = e0 + e1;
#pragma unroll
            for (int d = 1; d < 16; d <<= 1) su += __shfl_xor(su, d);
            float is = 1.0f / su;
            float p0 = e0 * is, p1 = e1 * is;
            const int gb = lane & 48;     // 16-lane group base
            int4 iv4 = *(const int4*)(inv + s2 * V_ + j0 * 4);
            int ivv[4] = {iv4.x, iv4.y, iv4.z, iv4.w};
            float o[4];
#pragma unroll
            for (int e = 0; e < 4; e++) {
                float ga = __shfl(p0, gb + (ivv[e] & 15));
                float gc = __shfl(p1, gb + (ivv[e] & 15));
                o[e] = (ivv[e] < 0) ? 0.f : ((ivv[e] < 16) ? ga : gc);
            }
            *(float4*)(out + ((size_t)(r0 + r) * T_ + (i - 2)) * V_ + j0 * 4) = *(float4*)o;
        }

        // ---- tanh + hi/lo split -> x[cur^1] (1 col-tile per wave) ----
        if (s0 >= 0) {
            float bv[4] = {bb1.x, bb1.y, bb1.z, bb1.w};
            bf16x4 hv, lv;
#pragma unroll
            for (int e = 0; e < 4; e++) {
                float h = fast_tanh(acc1[e] + bv[e]);
                bf16 hh = (bf16)h;
                hv[e] = hh;
                lv[e] = (bf16)(h - (float)hh);
            }
            const int a = xaddr(wave, q, n);
            *(bf16x4*)(&xh[cur ^ 1][a]) = hv;
            *(bf16x4*)(&xl[cur ^ 1][a]) = lv;
        }

        s2 = s1; s1 = s0; s0 = ns0;
        block_sync_lds();
    }
}

extern "C" void kernel_launch(void* const* d_in, const int* in_sizes, int n_in,
                              void* d_out, int out_size, void* d_ws, size_t ws_size,
                              hipStream_t stream) {
    const float* latent0   = (const float*)d_in[0];
    const float* W1        = (const float*)d_in[1];
    const float* b1        = (const float*)d_in[2];
    const float* W2        = (const float*)d_in[3];
    const float* b2        = (const float*)d_in[4];
    const int*   state_seq = (const int*)d_in[5];
    const int*   out_idx   = (const int*)d_in[6];
    float* out = (float*)d_out;

    bf16* W1h = (bf16*)d_ws;
    bf16* W1l = W1h + (size_t)NS * NL * NL;
    bf16* W2h = W1l + (size_t)NS * NL * NL;
    bf16* W2l = W2h + (size_t)NS * NO * NL;
    int*  inv = (int*)(W2l + (size_t)NS * NO * NL);

    const int n4_w1 = NS * NL * NL / 4;   // 1,048,576
    const int n4_w2 = NS * NO * NL / 4;   // 131,072
    split_w_frag<4><<<n4_w1 / 256, 256, 0, stream>>>(W1, W1h, W1l, n4_w1);
    split_w_frag<1><<<n4_w2 / 256, 256, 0, stream>>>(W2, W2h, W2l, n4_w2);
    inv_kernel<<<(NS * V_ + 255) / 256, 256, 0, stream>>>(out_idx, inv);

    lalr_main<<<NBLK, 1024, 0, stream>>>(latent0, b1, b2, state_seq, inv,
                                         W1h, W1l, W2h, W2l, out);
}

// Round 6
// 621.807 us; speedup vs baseline: 1.1303x; 1.1303x over previous
//
#include <hip/hip_runtime.h>

// Problem dims
#define B_  4096
#define T_  128
#define NL  256
#define NS  64
#define NO  32
#define V_  64
#define RB  16            // rows per block
#define NBLK (B_ / RB)    // 256 blocks

typedef __bf16 bf16;
typedef bf16  bf16x8 __attribute__((ext_vector_type(8)));
typedef bf16  bf16x4 __attribute__((ext_vector_type(4)));
typedef float f32x4  __attribute__((ext_vector_type(4)));

#define MF(a, b, c) __builtin_amdgcn_mfma_f32_16x16x32_bf16(a, b, c, 0, 0, 0)

// Barrier WITHOUT vmcnt drain: cross-barrier data is in VGPRs (weight ring);
// only LDS (x, Sp) needs ordering -> lgkmcnt(0)+s_barrier. __syncthreads()
// would emit s_waitcnt vmcnt(0) and drain the in-flight prefetch loads.
__device__ __forceinline__ void block_sync_lds() {
    asm volatile("s_waitcnt lgkmcnt(0)\ns_barrier" ::: "memory");
}

// ---------------------------------------------------------------------------
// Split fp32 weights -> bf16 hi/lo planes in MFMA A-fragment order:
//   dest[(((s*NT + t)*8 + ks)*512) + L*8 + j] = W[s][t*16 + (L&15)][ks*32 + (L>>4)*8 + j]
// so a wave's fragment load is one contiguous 1 KB global_load_dwordx4.
// ---------------------------------------------------------------------------
template <int TSHIFT>
__global__ void split_w_frag(const float* __restrict__ src,
                             bf16* __restrict__ hi, bf16* __restrict__ lo,
                             int total4) {
    int t4 = blockIdx.x * blockDim.x + threadIdx.x;
    if (t4 >= total4) return;
    const int jb   = (t4 & 1) * 4;
    const int L    = (t4 >> 1) & 63;
    const int ks   = (t4 >> 7) & 7;
    const int rest = t4 >> 10;
    const int t    = rest & ((1 << TSHIFT) - 1);
    const int s    = rest >> TSHIFT;
    const int row  = ((s << TSHIFT) + t) * 16 + (L & 15);
    const int k    = ks * 32 + (L >> 4) * 8 + jb;
    const float4 v = *(const float4*)(src + (size_t)row * NL + k);
    float vv[4] = {v.x, v.y, v.z, v.w};
    bf16x4 h, l;
#pragma unroll
    for (int e = 0; e < 4; e++) {
        bf16 hh = (bf16)vv[e];
        h[e] = hh;
        l[e] = (bf16)(vv[e] - (float)hh);
    }
    *(bf16x4*)(hi + (size_t)t4 * 4) = h;
    *(bf16x4*)(lo + (size_t)t4 * 4) = l;
}

// inv[s][v] = last j with out_idx[s][j]==v, else -1 (numpy last-dup-wins)
__global__ void inv_kernel(const int* __restrict__ out_idx, int* __restrict__ inv) {
    int t = blockIdx.x * blockDim.x + threadIdx.x;
    if (t >= NS * V_) return;
    int s = t >> 6, v = t & 63;
    int jf = -1;
#pragma unroll
    for (int j = 0; j < NO; j++)
        if (out_idx[(s << 5) | j] == v) jf = j;
    inv[t] = jf;
}

__device__ __forceinline__ float fast_tanh(float z) {
    float e = __expf(2.0f * z);
    return 1.0f - 2.0f / (e + 1.0f);
}

// x fragment-order address for element (batch row n, k = t*16 + q*4):
__device__ __forceinline__ int xaddr(int t, int q, int n) {
    return ((t >> 1) * 512) + (((t & 1) * 2 + (q >> 1)) * 128) + n * 8 + (q & 1) * 4;
}

// ---------------------------------------------------------------------------
// Persistent per-block recurrence. RB=16 rows/block, 256 blocks, 16 waves.
// Wave w: GEMM1 col-tile w (16 cols, 24 MFMA); GEMM2 task (t=w&1, ks=w>>1).
// One vmcnt-free barrier/step. 4-slot ROLLING weight ring: slot ks&3 is
// refilled right after consumption — with this step's ks+4 during ks=0..3,
// with NEXT step's ks-4 during ks=4..7 (those cross the barrier in flight).
// VMEM issue is even (2 loads / ks-iter); every load has >=4 ks-iters slack.
// ---------------------------------------------------------------------------
__launch_bounds__(1024, 4)
__global__ void lalr_main(const float* __restrict__ latent0,
                          const float* __restrict__ b1,
                          const float* __restrict__ b2,
                          const int*   __restrict__ state_seq,
                          const int*   __restrict__ inv,
                          const bf16*  __restrict__ W1h, const bf16* __restrict__ W1l,
                          const bf16*  __restrict__ W2h, const bf16* __restrict__ W2l,
                          float* __restrict__ out) {
    __shared__ bf16  xh[2][4096];        // 16 KB  (frag order, double buffered)
    __shared__ bf16  xl[2][4096];        // 16 KB
    __shared__ float Sp[2][8][16][36];   // 72 KB  GEMM2 K-partials (pad 36)

    const int tid  = threadIdx.x;
    const int wave = tid >> 6;           // 0..15
    const int lane = tid & 63;
    const int n    = lane & 15;          // batch row
    const int q    = lane >> 4;          // quad
    const int r0   = blockIdx.x * RB;
    const int t2   = wave & 1;           // GEMM2 col-tile
    const int ks2  = wave >> 1;          // GEMM2 K-slice

    // ---- init: latent0 -> x[0] fragments (1 float4 per thread) ----
    {
        float4 v = *(const float4*)(latent0 + (size_t)(r0 + n) * NL + wave * 16 + q * 4);
        float vv[4] = {v.x, v.y, v.z, v.w};
        bf16x4 hv, lv;
#pragma unroll
        for (int e = 0; e < 4; e++) {
            bf16 hh = (bf16)vv[e];
            hv[e] = hh;
            lv[e] = (bf16)(vv[e] - (float)hh);
        }
        const int a = xaddr(wave, q, n);
        *(bf16x4*)(&xh[0][a]) = hv;
        *(bf16x4*)(&xl[0][a]) = lv;
    }

    int s0 = state_seq[0], s1 = -1, s2 = -1;

    // current-step W1 base + 4-slot ring preload (ks=0..3 of s0)
    const bf16* w1hb = W1h + ((size_t)(s0 * 16 + wave) * 8) * 512;
    const bf16* w1lb = W1l + ((size_t)(s0 * 16 + wave) * 8) * 512;
    bf16x8 pwh[4], pwl[4];
#pragma unroll
    for (int p = 0; p < 4; p++) {
        pwh[p] = *(const bf16x8*)(w1hb + p * 512 + lane * 8);
        pwl[p] = *(const bf16x8*)(w1lb + p * 512 + lane * 8);
    }
    bf16x8 w2h2, w2l2;   // GEMM2 frags for next iteration

    block_sync_lds();

    for (int i = 0; i <= T_ + 1; i++) {
        const int ib  = i & 1;
        const int cur = ib;               // x buffer read this iteration

        const int ns0 = (i + 1 < T_) ? state_seq[i + 1] : -1;
        const int pfs = (ns0 >= 0) ? ns0 : 0;   // safe prefetch state
        const bf16* nw1hb = W1h + ((size_t)(pfs * 16 + wave) * 8) * 512;
        const bf16* nw1lb = W1l + ((size_t)(pfs * 16 + wave) * 8) * 512;

        // bias prefetch (full-loop distance to their uses)
        float4 bb1, bb2;
        if (s0 >= 0) bb1 = *(const float4*)(b1 + s0 * NL + wave * 16 + q * 4);
        if (s1 >= 0 && ks2 == 0)
            bb2 = *(const float4*)(b2 + s1 * NO + t2 * 16 + q * 4);

        // ---- GEMM1 (state s0): col-tile `wave`, K=256, rolling 4-slot ring ----
        f32x4 acc1;
        if (s0 >= 0) {
            acc1 = (f32x4){0.f, 0.f, 0.f, 0.f};
#pragma unroll
            for (int ks = 0; ks < 8; ks++) {
                bf16x8 xa = *(const bf16x8*)(&xh[cur][ks * 512 + lane * 8]);
                bf16x8 xb = *(const bf16x8*)(&xl[cur][ks * 512 + lane * 8]);
                const int sl = ks & 3;
                bf16x8 wh = pwh[sl], wl = pwl[sl];
                if (ks < 4) {   // refill with this step's ks+4
                    pwh[sl] = *(const bf16x8*)(w1hb + (ks + 4) * 512 + lane * 8);
                    pwl[sl] = *(const bf16x8*)(w1lb + (ks + 4) * 512 + lane * 8);
                } else {        // refill with NEXT step's ks-4 (crosses barrier in flight)
                    pwh[sl] = *(const bf16x8*)(nw1hb + (ks - 4) * 512 + lane * 8);
                    pwl[sl] = *(const bf16x8*)(nw1lb + (ks - 4) * 512 + lane * 8);
                }
                acc1 = MF(wh, xa, acc1);
                acc1 = MF(wl, xa, acc1);
                acc1 = MF(wh, xb, acc1);
            }
        }

        // ---- GEMM2 (state s1): task (t2, ks2) ----
        if (s1 >= 0) {
            bf16x8 xa = *(const bf16x8*)(&xh[cur][ks2 * 512 + lane * 8]);
            bf16x8 xb = *(const bf16x8*)(&xl[cur][ks2 * 512 + lane * 8]);
            f32x4 a2 = (f32x4){0.f, 0.f, 0.f, 0.f};
            a2 = MF(w2h2, xa, a2);
            a2 = MF(w2l2, xa, a2);
            a2 = MF(w2h2, xb, a2);
            if (ks2 == 0) {
                a2[0] += bb2.x; a2[1] += bb2.y; a2[2] += bb2.z; a2[3] += bb2.w;
            }
            *(f32x4*)(&Sp[ib][ks2][n][t2 * 16 + q * 4]) = a2;
        }

        // ---- W2 prefetch for next iteration (next iter's s1 = s0) ----
        if (s0 >= 0) {
            const bf16* w2hb = W2h + ((size_t)((s0 * 2 + t2) * 8 + ks2)) * 512;
            const bf16* w2lb = W2l + ((size_t)((s0 * 2 + t2) * 8 + ks2)) * 512;
            w2h2 = *(const bf16x8*)(w2hb + lane * 8);
            w2l2 = *(const bf16x8*)(w2lb + lane * 8);
        }

        // ---- softmax + shfl-scatter + store for step i-2 (first 4 waves) ----
        if (s2 >= 0 && tid < 256) {
            const int r  = tid >> 4;
            const int j0 = tid & 15;
            const int pb = (i - 1) & 1;
            float v0 = 0.f, v1 = 0.f;
#pragma unroll
            for (int w = 0; w < 8; w++) {
                v0 += Sp[pb][w][r][j0];
                v1 += Sp[pb][w][r][j0 + 16];
            }
            float m = fmaxf(v0, v1);
#pragma unroll
            for (int d = 1; d < 16; d <<= 1) m = fmaxf(m, __shfl_xor(m, d));
            float e0 = __expf(v0 - m), e1 = __expf(v1 - m);
            float su = e0 + e1;
#pragma unroll
            for (int d = 1; d < 16; d <<= 1) su += __shfl_xor(su, d);
            float is = 1.0f / su;
            float p0 = e0 * is, p1 = e1 * is;
            const int gb = lane & 48;     // 16-lane group base
            int4 iv4 = *(const int4*)(inv + s2 * V_ + j0 * 4);
            int ivv[4] = {iv4.x, iv4.y, iv4.z, iv4.w};
            float o[4];
#pragma unroll
            for (int e = 0; e < 4; e++) {
                float ga = __shfl(p0, gb + (ivv[e] & 15));
                float gc = __shfl(p1, gb + (ivv[e] & 15));
                o[e] = (ivv[e] < 0) ? 0.f : ((ivv[e] < 16) ? ga : gc);
            }
            *(float4*)(out + ((size_t)(r0 + r) * T_ + (i - 2)) * V_ + j0 * 4) = *(float4*)o;
        }

        // ---- tanh + hi/lo split -> x[cur^1] (1 col-tile per wave) ----
        if (s0 >= 0) {
            float bv[4] = {bb1.x, bb1.y, bb1.z, bb1.w};
            bf16x4 hv, lv;
#pragma unroll
            for (int e = 0; e < 4; e++) {
                float h = fast_tanh(acc1[e] + bv[e]);
                bf16 hh = (bf16)h;
                hv[e] = hh;
                lv[e] = (bf16)(h - (float)hh);
            }
            const int a = xaddr(wave, q, n);
            *(bf16x4*)(&xh[cur ^ 1][a]) = hv;
            *(bf16x4*)(&xl[cur ^ 1][a]) = lv;
        }

        // rotate: next step's W1 base becomes current
        w1hb = nw1hb;
        w1lb = nw1lb;
        s2 = s1; s1 = s0; s0 = ns0;
        block_sync_lds();
    }
}

extern "C" void kernel_launch(void* const* d_in, const int* in_sizes, int n_in,
                              void* d_out, int out_size, void* d_ws, size_t ws_size,
                              hipStream_t stream) {
    const float* latent0   = (const float*)d_in[0];
    const float* W1        = (const float*)d_in[1];
    const float* b1        = (const float*)d_in[2];
    const float* W2        = (const float*)d_in[3];
    const float* b2        = (const float*)d_in[4];
    const int*   state_seq = (const int*)d_in[5];
    const int*   out_idx   = (const int*)d_in[6];
    float* out = (float*)d_out;

    bf16* W1h = (bf16*)d_ws;
    bf16* W1l = W1h + (size_t)NS * NL * NL;
    bf16* W2h = W1l + (size_t)NS * NL * NL;
    bf16* W2l = W2h + (size_t)NS * NO * NL;
    int*  inv = (int*)(W2l + (size_t)NS * NO * NL);

    const int n4_w1 = NS * NL * NL / 4;   // 1,048,576
    const int n4_w2 = NS * NO * NL / 4;   // 131,072
    split_w_frag<4><<<n4_w1 / 256, 256, 0, stream>>>(W1, W1h, W1l, n4_w1);
    split_w_frag<1><<<n4_w2 / 256, 256, 0, stream>>>(W2, W2h, W2l, n4_w2);
    inv_kernel<<<(NS * V_ + 255) / 256, 256, 0, stream>>>(out_idx, inv);

    lalr_main<<<NBLK, 1024, 0, stream>>>(latent0, b1, b2, state_seq, inv,
                                         W1h, W1l, W2h, W2l, out);
}